// Round 1
// baseline (566.738 us; speedup 1.0000x reference)
//
#include <hip/hip_runtime.h>
#include <hip/hip_bf16.h>
#include <math.h>

// ---------------------------------------------------------------------------
// Sizes (fixed by the problem)
#define Bq 256
#define DIM_IN 1024
#define DIM_GLOBAL 1024
#define UNITS 512
#define DD 16
#define GG 8
// d_out layout: attention [256*512*16] | weights [256*256*512] | outputs [256*512*16]
#define ATT_ELEMS (256*512*16)       // 2,097,152
#define W_ELEMS   (256*256*512)      // 33,554,432

typedef __attribute__((ext_vector_type(8))) short bf16x8;
typedef __attribute__((ext_vector_type(4))) float f32x4;

__device__ __forceinline__ short f2bf(float f) {
    union { float f; unsigned u; } v; v.f = f;
    unsigned u = v.u;
    u += 0x7fffu + ((u >> 16) & 1u);   // round-to-nearest-even
    return (short)(u >> 16);
}

// ---------------------------------------------------------------------------
// C[M,N] = A[M,K] @ B[K,N] + bias[N].  fp32 in/out, bf16 MFMA compute.
// 64x64 tile, BK=32, 256 threads (4 waves, 2x2 wave grid, 2x2 16x16 frags each).
#define BK 32
#define ASTR 40   // shorts per row (32 + 8 pad); 80 B, 16B-divisible
#define BSTR 40

__global__ __launch_bounds__(256) void gemm_bias(
    const float* __restrict__ A, const float* __restrict__ B,
    const float* __restrict__ bias, float* __restrict__ C,
    int M, int N, int K)
{
    __shared__ __align__(16) short As[64 * ASTR];
    __shared__ __align__(16) short Bs[64 * BSTR];

    const int t = threadIdx.x;
    const int lane = t & 63;
    const int wave = t >> 6;
    const int m0 = blockIdx.y * 64;
    const int n0 = blockIdx.x * 64;

    const int wm = (wave >> 1) * 32;
    const int wn = (wave & 1) * 32;
    const int fl = lane & 15;
    const int ko = lane >> 4;          // 0..3 -> k chunk of 8

    f32x4 acc00 = {}, acc01 = {}, acc10 = {}, acc11 = {};

    // staging maps
    const int ar = t >> 2;             // A row in tile (0..63)
    const int aq = (t & 3) * 8;        // k offset
    const int bn = t & 63;             // B col in tile
    const int bk = (t >> 6) * 8;       // k offset

    for (int k0 = 0; k0 < K; k0 += BK) {
        __syncthreads();
        {   // stage A: 8 consecutive f32 along k -> bf16x8 -> one b128 write
            const float* src = A + (m0 + ar) * K + k0 + aq;
            float4 v0 = *(const float4*)(src);
            float4 v1 = *(const float4*)(src + 4);
            bf16x8 p;
            p[0]=f2bf(v0.x); p[1]=f2bf(v0.y); p[2]=f2bf(v0.z); p[3]=f2bf(v0.w);
            p[4]=f2bf(v1.x); p[5]=f2bf(v1.y); p[6]=f2bf(v1.z); p[7]=f2bf(v1.w);
            *(bf16x8*)(&As[ar * ASTR + aq]) = p;
        }
        {   // stage B transposed: 8 f32 strided along k (each load coalesced over n)
            const float* src = B + (k0 + bk) * N + n0 + bn;
            bf16x8 p;
            #pragma unroll
            for (int j = 0; j < 8; j++) p[j] = f2bf(src[j * N]);
            *(bf16x8*)(&Bs[bn * BSTR + bk]) = p;
        }
        __syncthreads();

        bf16x8 a0 = *(const bf16x8*)(&As[(wm + 0  + fl) * ASTR + ko * 8]);
        bf16x8 a1 = *(const bf16x8*)(&As[(wm + 16 + fl) * ASTR + ko * 8]);
        bf16x8 b0 = *(const bf16x8*)(&Bs[(wn + 0  + fl) * BSTR + ko * 8]);
        bf16x8 b1 = *(const bf16x8*)(&Bs[(wn + 16 + fl) * BSTR + ko * 8]);
        acc00 = __builtin_amdgcn_mfma_f32_16x16x32_bf16(a0, b0, acc00, 0, 0, 0);
        acc01 = __builtin_amdgcn_mfma_f32_16x16x32_bf16(a0, b1, acc01, 0, 0, 0);
        acc10 = __builtin_amdgcn_mfma_f32_16x16x32_bf16(a1, b0, acc10, 0, 0, 0);
        acc11 = __builtin_amdgcn_mfma_f32_16x16x32_bf16(a1, b1, acc11, 0, 0, 0);
    }

    // epilogue: C/D layout col=lane&15, row=(lane>>4)*4+reg (HW-verified mapping)
    #pragma unroll
    for (int r = 0; r < 4; r++) {
        int mrow = m0 + wm + ko * 4 + r;
        int ncol = n0 + wn + fl;
        C[(mrow     ) * N + (ncol     )] = acc00[r] + bias[ncol];
        C[(mrow     ) * N + (ncol + 16)] = acc01[r] + bias[ncol + 16];
        C[(mrow + 16) * N + (ncol     )] = acc10[r] + bias[ncol];
        C[(mrow + 16) * N + (ncol + 16)] = acc11[r] + bias[ncol + 16];
    }
}

// ---------------------------------------------------------------------------
// Fused: scores (bud,mud->bmu) * temperature, diag mask, grouped softmax over
// m ≡ g (mod 8) (32 elems/group), /8, weights write, PV einsum (bmu,mud->bud).
// Block = (8 b-rows) x (32 consecutive u). Thread owns one (b,u) pair.
#define L2E 1.4426950408889634f

__global__ __launch_bounds__(256) void attn_fused(
    const float* __restrict__ attention,   // [256,512,16]
    const float* __restrict__ mem_att,     // [256,512,16]
    const float* __restrict__ mem_val,     // [256,512,16]
    const float* __restrict__ temperature, // [512]
    float* __restrict__ weights_out,       // [256,256,512]
    float* __restrict__ outputs_out)       // [256,512,16]
{
    const int t = threadIdx.x;
    const int ublk = blockIdx.x & 15;      // 16 u-tiles of 32
    const int bblk = blockIdx.x >> 4;      // 32 b-tiles of 8
    const int u = ublk * 32 + (t & 31);
    const int b = bblk * 8 + (t >> 5);

    float att[16];
    {
        const float* ap = attention + (b * UNITS + u) * DD;
        #pragma unroll
        for (int d4 = 0; d4 < 4; d4++) {
            float4 v = *(const float4*)(ap + d4 * 4);
            att[d4*4+0]=v.x; att[d4*4+1]=v.y; att[d4*4+2]=v.z; att[d4*4+3]=v.w;
        }
    }
    const float temp = temperature[u];

    float gmax[8], gsum[8];
    #pragma unroll
    for (int g = 0; g < 8; g++) { gmax[g] = -1e30f; gsum[g] = 0.0f; }

    const float* kbase = mem_att + u * DD;

    // ---- pass 1: online max + sum(exp) per group (registers only) ----
    for (int m8 = 0; m8 < 256; m8 += 8) {
        #pragma unroll
        for (int g = 0; g < 8; g++) {
            const int m = m8 + g;
            const float* kp = kbase + m * (UNITS * DD);
            float s = 0.f;
            #pragma unroll
            for (int d4 = 0; d4 < 4; d4++) {
                float4 v = *(const float4*)(kp + d4 * 4);
                s += att[d4*4+0]*v.x + att[d4*4+1]*v.y
                   + att[d4*4+2]*v.z + att[d4*4+3]*v.w;
            }
            s *= temp;
            const bool masked = (m == b);
            const float se = masked ? -1e30f : s;
            const float nm = fmaxf(gmax[g], se);
            const float e  = masked ? 0.f : exp2f((se - nm) * L2E);
            gsum[g] = gsum[g] * exp2f((gmax[g] - nm) * L2E) + e;
            gmax[g] = nm;
        }
    }

    float rinv[8];
    #pragma unroll
    for (int g = 0; g < 8; g++) rinv[g] = 1.0f / (8.0f * gsum[g]);

    float acc[16];
    #pragma unroll
    for (int d = 0; d < 16; d++) acc[d] = 0.f;

    const float* vbase = mem_val + u * DD;
    float* wrow = weights_out + b * (256 * UNITS) + u;

    // ---- pass 2: recompute score, write weights, accumulate outputs ----
    for (int m8 = 0; m8 < 256; m8 += 8) {
        #pragma unroll
        for (int g = 0; g < 8; g++) {
            const int m = m8 + g;
            const float* kp = kbase + m * (UNITS * DD);
            float s = 0.f;
            #pragma unroll
            for (int d4 = 0; d4 < 4; d4++) {
                float4 v = *(const float4*)(kp + d4 * 4);
                s += att[d4*4+0]*v.x + att[d4*4+1]*v.y
                   + att[d4*4+2]*v.z + att[d4*4+3]*v.w;
            }
            s *= temp;
            const float w = (m == b) ? 0.f
                           : exp2f((s - gmax[g]) * L2E) * rinv[g];
            wrow[m * UNITS] = w;   // lanes 0..31 -> 128 B contiguous, aligned
            const float* vp = vbase + m * (UNITS * DD);
            #pragma unroll
            for (int d4 = 0; d4 < 4; d4++) {
                float4 v = *(const float4*)(vp + d4 * 4);
                acc[d4*4+0] += w * v.x; acc[d4*4+1] += w * v.y;
                acc[d4*4+2] += w * v.z; acc[d4*4+3] += w * v.w;
            }
        }
    }

    float* op = outputs_out + (b * UNITS + u) * DD;
    #pragma unroll
    for (int d4 = 0; d4 < 4; d4++) {
        float4 v;
        v.x = acc[d4*4+0]; v.y = acc[d4*4+1];
        v.z = acc[d4*4+2]; v.w = acc[d4*4+3];
        *(float4*)(op + d4 * 4) = v;
    }
}

// ---------------------------------------------------------------------------
extern "C" void kernel_launch(void* const* d_in, const int* in_sizes, int n_in,
                              void* d_out, int out_size, void* d_ws, size_t ws_size,
                              hipStream_t stream) {
    const float* x        = (const float*)d_in[0];  // [256,1024]
    const float* W1       = (const float*)d_in[1];  // [1024,1024]
    const float* b1       = (const float*)d_in[2];  // [1024]
    const float* W2       = (const float*)d_in[3];  // [1024,8192]
    const float* b2       = (const float*)d_in[4];  // [8192]
    const float* temp     = (const float*)d_in[5];  // [512]
    const float* mem_att  = (const float*)d_in[6];  // [256,512,16]
    const float* mem_val  = (const float*)d_in[7];  // [256,512,16]

    float* out       = (float*)d_out;
    float* attention = out;                         // 2,097,152 floats
    float* weights   = out + ATT_ELEMS;             // 33,554,432 floats
    float* outputs   = out + ATT_ELEMS + W_ELEMS;   // 2,097,152 floats

    // h [256,1024] scratch lives at the head of the weights region; it is
    // consumed by GEMM2 before attn_fused overwrites the region.
    float* h = weights;

    dim3 blk(256);
    // h = x @ W1 + b1
    gemm_bias<<<dim3(DIM_GLOBAL / 64, Bq / 64), blk, 0, stream>>>(
        x, W1, b1, h, Bq, DIM_GLOBAL, DIM_IN);
    // attention = h @ W2 + b2
    gemm_bias<<<dim3((UNITS * DD) / 64, Bq / 64), blk, 0, stream>>>(
        h, W2, b2, attention, Bq, UNITS * DD, DIM_GLOBAL);
    // fused scores -> grouped softmax -> weights + outputs
    attn_fused<<<dim3(512), blk, 0, stream>>>(
        attention, mem_att, mem_val, temp, weights, outputs);
}